// Round 1
// 487.833 us; speedup vs baseline: 1.2842x; 1.2842x over previous
//
#include <hip/hip_runtime.h>

#define L_DIM 16384
#define C_DIM 256
#define NV 8
#define NH 4
#define DH 64
#define TL 4          // l's per block (32 token rows)
#define NTHREADS 256  // 4 waves

// LDS strides (in elements)
#define QKP 132       // f16 per row for q|k  (264 B row, 66 words % 32 = 2)
#define VVP 68        // f16 per row for v    (136 B row, 34 words % 32 = 2)
#define GPAD 65       // fp32 per row for g1s
// A/ctx/att: 32 rows x 256 f16, 16B slots XOR-swizzled: slot' = slot ^ (row&31)

typedef __attribute__((ext_vector_type(8))) _Float16 f16x8;
typedef __attribute__((ext_vector_type(4))) float f32x4;

// ---------------- prep: view_info + pack fp16 weights into MFMA fragment order
// Packed layout: frag index ((chunk*4 + nt)*8 + kc)*64 + lane, 8 f16 each.
// Element j = W[chunkrow + nt*16 + (lane&15)][(lane>>4)*8 + kc*32 + j].
__global__ void prep_kernel(const float* __restrict__ vw, const float* __restrict__ vb,
                            const float* __restrict__ w_in, const float* __restrict__ w_out,
                            const float* __restrict__ w_g1,
                            float* __restrict__ view_info, _Float16* __restrict__ win_pk,
                            _Float16* __restrict__ wout_pk, _Float16* __restrict__ wg1_pk){
  int tid = threadIdx.x, bid = blockIdx.x;
  if (bid == 0){
    int c = tid;                       // 256 threads, one channel each
    const float4* vr = (const float4*)(vw + c*C_DIM);
    float rs = 0.f;
#pragma unroll 8
    for (int k = 0; k < 64; k++){ float4 x = vr[k]; rs += x.x + x.y + x.z + x.w; }
    float b = vb[c];
    for (int n = 0; n < NV; n++) view_info[n*C_DIM + c] = (n * 0.125f) * rs + b;
  }
  int gid = bid * blockDim.x + tid;
  int stride = gridDim.x * blockDim.x;
  const int NWIN = 24576, NWOUT = 8192, NWG = 2048;
  for (int f = gid; f < NWIN + NWOUT + NWG; f += stride){
    if (f < NWIN){
      int lane = f & 63, kc = (f>>6)&7, nt = (f>>9)&3, pc = f>>11;   // pc = h*3+p
      int p = pc % 3, h = pc / 3;
      int row = p*C_DIM + h*DH + nt*16 + (lane&15);
      int col = (lane>>4)*8 + kc*32;
      const float* src = w_in + (long)row*C_DIM + col;
      _Float16* d = win_pk + (long)f*8;
#pragma unroll
      for (int j = 0; j < 8; j++) d[j] = (_Float16)src[j];
    } else if (f < NWIN + NWOUT){
      int f2 = f - NWIN;
      int lane = f2 & 63, kc = (f2>>6)&7, nt = (f2>>9)&3, cc = f2>>11;
      int row = cc*64 + nt*16 + (lane&15);
      int col = (lane>>4)*8 + kc*32;
      const float* src = w_out + (long)row*C_DIM + col;
      _Float16* d = wout_pk + (long)f2*8;
#pragma unroll
      for (int j = 0; j < 8; j++) d[j] = (_Float16)src[j];
    } else {
      int f3 = f - NWIN - NWOUT;
      int lane = f3 & 63, kc = (f3>>6)&7, nt = (f3>>9)&3;
      int row = nt*16 + (lane&15);
      int col = (lane>>4)*8 + kc*32;
      const float* src = w_g1 + (long)row*C_DIM + col;
      _Float16* d = wg1_pk + (long)f3*8;
#pragma unroll
      for (int j = 0; j < 8; j++) d[j] = (_Float16)src[j];
    }
  }
}

// ---------------- fused main kernel: one block = 4 l's (32 tokens), 4 waves ----
// fp16 single-term everywhere. A staged in LDS once (no per-wave ahi registers).
// LDS carve (46880 B -> 3 blocks/CU):
//   [0,16384)      A [32][256]h swz   | att overlay (out-proj output)
//   [16384,24832)  qk [32][132]h      | g1s [32][65]f overlay
//   [24832,29184)  vv [32][68]h
//   [29184,45568)  ctx [32][256]h swz
//   [45568,46880)  misc: gl[32], wgt[32], red1[128], red2[128], mus[4], rvs[4]
__global__ __launch_bounds__(NTHREADS, 3)
void fused_kernel(const float* __restrict__ feat,
                  const float* __restrict__ view_info,
                  const _Float16* __restrict__ win,
                  const _Float16* __restrict__ wout,
                  const _Float16* __restrict__ wg1,
                  const float* __restrict__ b_in,
                  const float* __restrict__ b_out,
                  const float* __restrict__ b_g1,
                  const float* __restrict__ w2,
                  const float* __restrict__ b2,
                  const float* __restrict__ ln_g,
                  const float* __restrict__ ln_b,
                  float* __restrict__ out)
{
  extern __shared__ char smem[];
  _Float16* A   = (_Float16*)smem;             // [32][256] swz
  _Float16* att = (_Float16*)smem;             // overlay after A dead
  _Float16* qk  = (_Float16*)(smem + 16384);   // [32][132]
  float*    g1s = (float*)(smem + 16384);      // overlay after qk dead
  _Float16* vv  = (_Float16*)(smem + 24832);   // [32][68]
  _Float16* ctx = (_Float16*)(smem + 29184);   // [32][256] swz
  float* gl   = (float*)(smem + 45568);        // [32]
  float* wgt  = gl + 32;                       // [32]
  float* red1 = wgt + 32;                      // [128]
  float* red2 = red1 + 128;                    // [128]
  float* mus  = red2 + 128;                    // [4]
  float* rvs  = mus + 4;                       // [4]

  const int tid  = threadIdx.x;
  const int wv   = tid >> 6, lane = tid & 63;
  const int quad = lane >> 4, l15 = lane & 15;

  // ---- stage A = f16(features + view_info) into LDS, cooperative (once) ----
  {
    int row = tid >> 3, j = tid & 7;            // 32 rows x 8 threads
    int n = row & 7, lloc = row >> 3;
    long l = (long)blockIdx.x * TL + lloc;
    const float* fb = feat + ((long)n * L_DIM + l) * C_DIM + j*32;
    const float* vb = view_info + n * C_DIM + j*32;
    _Float16* arow = A + row*256;
#pragma unroll
    for (int i = 0; i < 4; i++){
      float4 x0 = *(const float4*)(fb + i*8);
      float4 x1 = *(const float4*)(fb + i*8 + 4);
      float4 v0 = *(const float4*)(vb + i*8);
      float4 v1 = *(const float4*)(vb + i*8 + 4);
      f16x8 hf;
      hf[0] = (_Float16)(x0.x+v0.x); hf[1] = (_Float16)(x0.y+v0.y);
      hf[2] = (_Float16)(x0.z+v0.z); hf[3] = (_Float16)(x0.w+v0.w);
      hf[4] = (_Float16)(x1.x+v1.x); hf[5] = (_Float16)(x1.y+v1.y);
      hf[6] = (_Float16)(x1.z+v1.z); hf[7] = (_Float16)(x1.w+v1.w);
      int s = j*4 + i;
      *(f16x8*)(arow + ((s ^ row))*8) = hf;
    }
  }
  __syncthreads();

  // ================= per-head: qkv GEMM (single fp16 term) + attention =========
  for (int h = 0; h < NH; h++){
    if (h) __syncthreads();                 // prior attention done reading qk/vv
    {
      const _Float16* bp = win + (long)(h*96 + wv*8)*512 + lane*8;
      f32x4 z = {0.f,0.f,0.f,0.f};
      f32x4 acc[3][2];
#pragma unroll
      for (int p = 0; p < 3; p++){ acc[p][0] = z; acc[p][1] = z; }
#pragma unroll
      for (int kc = 0; kc < 8; kc++){
        int s0 = quad + 4*kc;
        int r1 = 16 + l15;
        f16x8 a0 = *(const f16x8*)(A + l15*256 + ((s0 ^ l15))*8);
        f16x8 a1 = *(const f16x8*)(A + r1*256  + ((s0 ^ r1))*8);
#pragma unroll
        for (int p = 0; p < 3; p++){
          f16x8 b = *(const f16x8*)(bp + (p*32 + kc)*512);
          acc[p][0] = __builtin_amdgcn_mfma_f32_16x16x32_f16(a0, b, acc[p][0], 0,0,0);
          acc[p][1] = __builtin_amdgcn_mfma_f32_16x16x32_f16(a1, b, acc[p][1], 0,0,0);
        }
      }
      int colc = wv*16 + l15;               // 0..63 within chunk
#pragma unroll
      for (int p = 0; p < 2; p++){
        float bias = b_in[p*C_DIM + h*DH + colc];
#pragma unroll
        for (int r = 0; r < 4; r++){
          qk[(quad*4 + r)*QKP + p*64 + colc]      = (_Float16)(acc[p][0][r] + bias);
          qk[(16 + quad*4 + r)*QKP + p*64 + colc] = (_Float16)(acc[p][1][r] + bias);
        }
      }
      {
        float bias = b_in[2*C_DIM + h*DH + colc];
#pragma unroll
        for (int r = 0; r < 4; r++){
          vv[(quad*4 + r)*VVP + colc]      = (_Float16)(acc[2][0][r] + bias);
          vv[(16 + quad*4 + r)*VVP + colc] = (_Float16)(acc[2][1][r] + bias);
        }
      }
    }
    __syncthreads();                        // q,k,v complete for this head
    // ---- attention for head h: wave wv handles l_loc = wv, lane = nn*8+mm ----
    {
      int nn = lane >> 3, mm = lane & 7;
      int tq = wv*8 + nn;
      const _Float16* qrow = qk + tq*QKP;              // broadcast over mm
      const _Float16* krow = qk + (wv*8 + mm)*QKP + 64;
      float s = 0.f;
#pragma unroll
      for (int d8 = 0; d8 < 8; d8++){
        f16x8 q8 = *(const f16x8*)(qrow + d8*8);
        f16x8 k8 = *(const f16x8*)(krow + d8*8);
#pragma unroll
        for (int j = 0; j < 8; j++) s += (float)q8[j] * (float)k8[j];
      }
      s *= 0.125f;                          // 1/sqrt(64)
      float mx = s;
#pragma unroll
      for (int o = 1; o < 8; o <<= 1) mx = fmaxf(mx, __shfl_xor(mx, o));
      float e = __expf(s - mx);
      float sum = e;
#pragma unroll
      for (int o = 1; o < 8; o <<= 1) sum += __shfl_xor(sum, o);
      float attnw = e / sum;
      // ctx: this thread owns d-slice [mm*8, mm*8+8) of token tq
      float c8[8] = {0,0,0,0,0,0,0,0};
#pragma unroll
      for (int mp = 0; mp < 8; mp++){
        float aw = __shfl(attnw, (nn<<3) | mp);
        f16x8 v8 = *(const f16x8*)(vv + (wv*8 + mp)*VVP + mm*8);
#pragma unroll
        for (int j = 0; j < 8; j++) c8[j] += aw * (float)v8[j];
      }
      f16x8 cp;
#pragma unroll
      for (int j = 0; j < 8; j++) cp[j] = (_Float16)c8[j];
      int slot = h*8 + mm;                  // 16B slot, XOR-swizzled
      *(f16x8*)(ctx + tq*256 + ((slot ^ (tq & 31)))*8) = cp;
    }
  }
  __syncthreads();  // ctx complete; A dead -> att may be written

  // ================= attended = ctx @ W_out^T + b_out (fp16 MFMA) =============
  {
    f32x4 z = {0.f,0.f,0.f,0.f};
    f32x4 acc[4][2];
#pragma unroll
    for (int nt = 0; nt < 4; nt++){ acc[nt][0] = z; acc[nt][1] = z; }
#pragma unroll
    for (int kc = 0; kc < 8; kc++){
      int s0 = quad + 4*kc;
      int r1 = 16 + l15;
      f16x8 a0 = *(const f16x8*)(ctx + l15*256 + ((s0 ^ l15))*8);
      f16x8 a1 = *(const f16x8*)(ctx + r1*256  + ((s0 ^ r1))*8);
#pragma unroll
      for (int nt = 0; nt < 4; nt++){
        f16x8 b = *(const f16x8*)(wout + (long)((wv*32 + nt*8 + kc)*512) + lane*8);
        acc[nt][0] = __builtin_amdgcn_mfma_f32_16x16x32_f16(a0, b, acc[nt][0], 0,0,0);
        acc[nt][1] = __builtin_amdgcn_mfma_f32_16x16x32_f16(a1, b, acc[nt][1], 0,0,0);
      }
    }
#pragma unroll
    for (int nt = 0; nt < 4; nt++){
      int col = wv*64 + nt*16 + l15;
      float bias = b_out[col];
      int slot = col >> 3, j = col & 7;
#pragma unroll
      for (int r = 0; r < 4; r++){
        int row0 = quad*4 + r, row1 = 16 + quad*4 + r;
        att[row0*256 + ((slot ^ row0))*8 + j] = (_Float16)(acc[nt][0][r] + bias);
        att[row1*256 + ((slot ^ row1))*8 + j] = (_Float16)(acc[nt][1][r] + bias);
      }
    }
  }
  __syncthreads();  // att ready; qk dead -> g1s may be written

  // ================= gate hidden: g1 = relu(att @ Wg1^T + b) =================
  {
    f32x4 acc0 = {0.f,0.f,0.f,0.f}, acc1 = {0.f,0.f,0.f,0.f};
#pragma unroll
    for (int kc = 0; kc < 8; kc++){
      int s0 = quad + 4*kc;
      int r1 = 16 + l15;
      f16x8 a0 = *(const f16x8*)(att + l15*256 + ((s0 ^ l15))*8);
      f16x8 a1 = *(const f16x8*)(att + r1*256  + ((s0 ^ r1))*8);
      f16x8 b = *(const f16x8*)(wg1 + (long)((wv*8 + kc)*512) + lane*8);
      acc0 = __builtin_amdgcn_mfma_f32_16x16x32_f16(a0, b, acc0, 0,0,0);
      acc1 = __builtin_amdgcn_mfma_f32_16x16x32_f16(a1, b, acc1, 0,0,0);
    }
    int col = wv*16 + l15;                  // 0..63
    float bias = b_g1[col];
#pragma unroll
    for (int r = 0; r < 4; r++){
      g1s[(quad*4 + r)*GPAD + col]      = fmaxf(acc0[r] + bias, 0.f);
      g1s[(16 + quad*4 + r)*GPAD + col] = fmaxf(acc1[r] + bias, 0.f);
    }
  }
  __syncthreads();

  // ---- gate scalar + sigmoid (8 threads per token, 32 tokens) ----
  {
    int t = tid >> 3, part = tid & 7;
    const float* g1r = g1s + t*GPAD + part*8;
    const float* w2p = w2 + part*8;
    float s = 0.f;
#pragma unroll
    for (int j = 0; j < 8; j++) s += g1r[j] * w2p[j];
    s += __shfl_xor(s, 1);
    s += __shfl_xor(s, 2);
    s += __shfl_xor(s, 4);
    if (part == 0) gl[t] = 1.f / (1.f + __expf(-(s + b2[0])));
  }
  __syncthreads();
  // ---- softmax over views (4 l's) ----
  if (tid < 4){
    float v[8]; float mx = -1e30f;
    for (int n = 0; n < 8; n++){ v[n] = gl[tid*8+n]; mx = fmaxf(mx, v[n]); }
    float sum = 0.f;
    for (int n = 0; n < 8; n++){ v[n] = __expf(v[n]-mx); sum += v[n]; }
    float inv = 1.f/sum;
    for (int n = 0; n < 8; n++) wgt[tid*8+n] = v[n]*inv;
  }
  __syncthreads();

  // ---- fused = sum_n w_n * attended, then LayerNorm over C ----
  float f8[8];
  const int lfl = tid >> 5, ccf = tid & 31;   // lfl 0..3 valid (tid<128)
  if (tid < 128){
    float wloc[8];
#pragma unroll
    for (int n = 0; n < 8; n++) wloc[n] = wgt[lfl*8+n];
#pragma unroll
    for (int j = 0; j < 8; j++) f8[j] = 0.f;
#pragma unroll
    for (int n = 0; n < 8; n++){
      int row = lfl*8 + n;
      f16x8 a8 = *(const f16x8*)(att + row*256 + ((ccf ^ row))*8);
      float aw = wloc[n];
#pragma unroll
      for (int j = 0; j < 8; j++) f8[j] += aw * (float)a8[j];
    }
    float s = 0.f, s2 = 0.f;
#pragma unroll
    for (int j = 0; j < 8; j++){ s += f8[j]; s2 += f8[j]*f8[j]; }
    red1[lfl*32 + ccf] = s;
    red2[lfl*32 + ccf] = s2;
  }
  __syncthreads();
  if (tid < 4){
    float s = 0.f, s2 = 0.f;
    for (int i = 0; i < 32; i++){ s += red1[tid*32+i]; s2 += red2[tid*32+i]; }
    float mu = s * (1.f/256.f);
    float var = s2 * (1.f/256.f) - mu*mu;
    mus[tid] = mu;
    rvs[tid] = rsqrtf(var + 1e-5f);
  }
  __syncthreads();
  if (tid < 128){
    float mu = mus[lfl], rv = rvs[lfl];
    long lg = (long)blockIdx.x * TL + lfl;
    float* op = out + lg * C_DIM + ccf*8;
    float o8[8];
#pragma unroll
    for (int j = 0; j < 8; j++){
      int c = ccf*8 + j;
      o8[j] = (f8[j]-mu)*rv*ln_g[c] + ln_b[c];
    }
    *(float4*)(op)   = make_float4(o8[0],o8[1],o8[2],o8[3]);
    *(float4*)(op+4) = make_float4(o8[4],o8[5],o8[6],o8[7]);
  }
}

extern "C" void kernel_launch(void* const* d_in, const int* in_sizes, int n_in,
                              void* d_out, int out_size, void* d_ws, size_t ws_size,
                              hipStream_t stream){
  const float* feat  = (const float*)d_in[0];
  const float* vw    = (const float*)d_in[1];
  const float* vb    = (const float*)d_in[2];
  const float* w_in  = (const float*)d_in[3];
  const float* b_in  = (const float*)d_in[4];
  const float* w_out = (const float*)d_in[5];
  const float* b_out = (const float*)d_in[6];
  const float* w_g1  = (const float*)d_in[7];
  const float* b_g1  = (const float*)d_in[8];
  const float* w2    = (const float*)d_in[9];
  const float* b2    = (const float*)d_in[10];
  const float* lng   = (const float*)d_in[11];
  const float* lnb   = (const float*)d_in[12];

  char* ws = (char*)d_ws;
  float*    view_info = (float*)ws;               //   8192 B
  _Float16* win_pk  = (_Float16*)(ws + 8192);     // 393216 B (packed fp16)
  _Float16* wout_pk = (_Float16*)(ws + 401408);   // 131072 B
  _Float16* wg1_pk  = (_Float16*)(ws + 532480);   //  32768 B   total 565248 B

  prep_kernel<<<256, 256, 0, stream>>>(vw, vb, w_in, w_out, w_g1,
                                       view_info, win_pk, wout_pk, wg1_pk);
  fused_kernel<<<L_DIM/TL, NTHREADS, 46880, stream>>>(
      feat, view_info, win_pk, wout_pk, wg1_pk,
      b_in, b_out, b_g1, w2, b2, lng, lnb, (float*)d_out);
}

// Round 2
// 431.148 us; speedup vs baseline: 1.4530x; 1.1315x over previous
//
#include <hip/hip_runtime.h>

#define L_DIM 16384
#define C_DIM 256
#define NV 8
#define NH 4
#define DH 64
#define TL 4          // l's per block (32 token rows)
#define NTHREADS 256  // 4 waves

// LDS strides (in elements)
#define QKP 132       // f16 per row for q|k  (264 B row, 66 words % 32 = 2)
#define VVP 68        // f16 per row for v    (136 B row, 34 words % 32 = 2)
#define GPAD 65       // fp32 per row for g1s
// A/ctx/att: 32 rows x 256 f16, 16B slots XOR-swizzled: slot' = slot ^ row

typedef __attribute__((ext_vector_type(8))) _Float16 f16x8;
typedef __attribute__((ext_vector_type(2))) _Float16 f16x2;
typedef __attribute__((ext_vector_type(4))) float f32x4;

union F8u { f16x8 v; f16x2 p[4]; };

// ---------------- prep: view_info + pack fp16 weights into MFMA fragment order
// Packed layout: frag index ((chunk*4 + nt)*8 + kc)*64 + lane, 8 f16 each.
// Element j = W[chunkrow + nt*16 + (lane&15)][(lane>>4)*8 + kc*32 + j].
__global__ void prep_kernel(const float* __restrict__ vw, const float* __restrict__ vb,
                            const float* __restrict__ w_in, const float* __restrict__ w_out,
                            const float* __restrict__ w_g1,
                            float* __restrict__ view_info, _Float16* __restrict__ win_pk,
                            _Float16* __restrict__ wout_pk, _Float16* __restrict__ wg1_pk){
  int tid = threadIdx.x, bid = blockIdx.x;
  if (bid == 0){
    int c = tid;                       // 256 threads, one channel each
    const float4* vr = (const float4*)(vw + c*C_DIM);
    float rs = 0.f;
#pragma unroll 8
    for (int k = 0; k < 64; k++){ float4 x = vr[k]; rs += x.x + x.y + x.z + x.w; }
    float b = vb[c];
    for (int n = 0; n < NV; n++) view_info[n*C_DIM + c] = (n * 0.125f) * rs + b;
  }
  int gid = bid * blockDim.x + tid;
  int stride = gridDim.x * blockDim.x;
  const int NWIN = 24576, NWOUT = 8192, NWG = 2048;
  for (int f = gid; f < NWIN + NWOUT + NWG; f += stride){
    if (f < NWIN){
      int lane = f & 63, kc = (f>>6)&7, nt = (f>>9)&3, pc = f>>11;   // pc = h*3+p
      int p = pc % 3, h = pc / 3;
      int row = p*C_DIM + h*DH + nt*16 + (lane&15);
      int col = (lane>>4)*8 + kc*32;
      const float* src = w_in + (long)row*C_DIM + col;
      _Float16* d = win_pk + (long)f*8;
#pragma unroll
      for (int j = 0; j < 8; j++) d[j] = (_Float16)src[j];
    } else if (f < NWIN + NWOUT){
      int f2 = f - NWIN;
      int lane = f2 & 63, kc = (f2>>6)&7, nt = (f2>>9)&3, cc = f2>>11;
      int row = cc*64 + nt*16 + (lane&15);
      int col = (lane>>4)*8 + kc*32;
      const float* src = w_out + (long)row*C_DIM + col;
      _Float16* d = wout_pk + (long)f2*8;
#pragma unroll
      for (int j = 0; j < 8; j++) d[j] = (_Float16)src[j];
    } else {
      int f3 = f - NWIN - NWOUT;
      int lane = f3 & 63, kc = (f3>>6)&7, nt = (f3>>9)&3;
      int row = nt*16 + (lane&15);
      int col = (lane>>4)*8 + kc*32;
      const float* src = w_g1 + (long)row*C_DIM + col;
      _Float16* d = wg1_pk + (long)f3*8;
#pragma unroll
      for (int j = 0; j < 8; j++) d[j] = (_Float16)src[j];
    }
  }
}

// ---------------- fused main kernel: one block = 4 l's (32 tokens), 4 waves ----
// LDS carve (34080 B -> 4 blocks/CU):
//   region1 [0,16384):      A [32][256]h swz -> ctx overlay -> g1s overlay
//   region2 [16384,32768):  qk [32][132]h + vv [32][68]h at +8448 -> att overlay
//   misc    [32768,34080):  gl[32], wgt[32], red1[128], red2[128], mus[4], rvs[4]
__global__ __launch_bounds__(NTHREADS, 4)
void fused_kernel(const float* __restrict__ feat,
                  const float* __restrict__ view_info,
                  const _Float16* __restrict__ win,
                  const _Float16* __restrict__ wout,
                  const _Float16* __restrict__ wg1,
                  const float* __restrict__ b_in,
                  const float* __restrict__ b_out,
                  const float* __restrict__ b_g1,
                  const float* __restrict__ w2,
                  const float* __restrict__ b2,
                  const float* __restrict__ ln_g,
                  const float* __restrict__ ln_b,
                  float* __restrict__ out)
{
  extern __shared__ char smem[];
  _Float16* A   = (_Float16*)smem;             // [32][256] swz
  _Float16* ctx = (_Float16*)smem;             // overlay after A dead
  float*    g1s = (float*)smem;                // overlay after ctx dead
  _Float16* qk  = (_Float16*)(smem + 16384);   // [32][132]
  _Float16* vv  = (_Float16*)(smem + 24832);   // [32][68]
  _Float16* att = (_Float16*)(smem + 16384);   // overlay after qk/vv dead
  float* gl   = (float*)(smem + 32768);        // [32]
  float* wgt  = gl + 32;                       // [32]
  float* red1 = wgt + 32;                      // [128]
  float* red2 = red1 + 128;                    // [128]
  float* mus  = red2 + 128;                    // [4]
  float* rvs  = mus + 4;                       // [4]

  const int tid  = threadIdx.x;
  const int wv   = tid >> 6, lane = tid & 63;
  const int quad = lane >> 4, l15 = lane & 15;

  // ---- stage A = f16(features + view_info) into LDS, cooperative (once) ----
  {
    int row = tid >> 3, j = tid & 7;            // 32 rows x 8 threads
    int n = row & 7, lloc = row >> 3;
    long l = (long)blockIdx.x * TL + lloc;
    const float* fb = feat + ((long)n * L_DIM + l) * C_DIM + j*32;
    const float* vb = view_info + n * C_DIM + j*32;
    _Float16* arow = A + row*256;
#pragma unroll
    for (int i = 0; i < 4; i++){
      float4 x0 = *(const float4*)(fb + i*8);
      float4 x1 = *(const float4*)(fb + i*8 + 4);
      float4 v0 = *(const float4*)(vb + i*8);
      float4 v1 = *(const float4*)(vb + i*8 + 4);
      f16x8 hf;
      hf[0] = (_Float16)(x0.x+v0.x); hf[1] = (_Float16)(x0.y+v0.y);
      hf[2] = (_Float16)(x0.z+v0.z); hf[3] = (_Float16)(x0.w+v0.w);
      hf[4] = (_Float16)(x1.x+v1.x); hf[5] = (_Float16)(x1.y+v1.y);
      hf[6] = (_Float16)(x1.z+v1.z); hf[7] = (_Float16)(x1.w+v1.w);
      int s = j*4 + i;
      *(f16x8*)(arow + ((s ^ row))*8) = hf;
    }
  }
  __syncthreads();

  // ================= per-head: qkv GEMM + attention (ctx kept in registers) ====
  f16x8 cpk0, cpk1, cpk2;
#pragma unroll
  for (int h = 0; h < NH; h++){
    if (h) __syncthreads();                 // prior attention done reading qk/vv
    {
      const _Float16* bp = win + (long)(h*96 + wv*8)*512 + lane*8;
      f32x4 z = {0.f,0.f,0.f,0.f};
      f32x4 acc00=z, acc01=z, acc10=z, acc11=z, acc20=z, acc21=z;
      f16x8 bq0 = *(const f16x8*)(bp);
      f16x8 bq1 = *(const f16x8*)(bp + 32*512);
      f16x8 bq2 = *(const f16x8*)(bp + 64*512);
#pragma unroll
      for (int kc = 0; kc < 8; kc++){
        f16x8 bn0, bn1, bn2;
        if (kc < 7){                         // depth-1 prefetch of next kc frags
          bn0 = *(const f16x8*)(bp + (kc+1)*512);
          bn1 = *(const f16x8*)(bp + (32+kc+1)*512);
          bn2 = *(const f16x8*)(bp + (64+kc+1)*512);
        }
        int s0 = quad + 4*kc;
        int r1 = 16 + l15;
        f16x8 a0 = *(const f16x8*)(A + l15*256 + ((s0 ^ l15))*8);
        f16x8 a1 = *(const f16x8*)(A + r1*256  + ((s0 ^ r1))*8);
        acc00 = __builtin_amdgcn_mfma_f32_16x16x32_f16(a0, bq0, acc00, 0,0,0);
        acc01 = __builtin_amdgcn_mfma_f32_16x16x32_f16(a1, bq0, acc01, 0,0,0);
        acc10 = __builtin_amdgcn_mfma_f32_16x16x32_f16(a0, bq1, acc10, 0,0,0);
        acc11 = __builtin_amdgcn_mfma_f32_16x16x32_f16(a1, bq1, acc11, 0,0,0);
        acc20 = __builtin_amdgcn_mfma_f32_16x16x32_f16(a0, bq2, acc20, 0,0,0);
        acc21 = __builtin_amdgcn_mfma_f32_16x16x32_f16(a1, bq2, acc21, 0,0,0);
        bq0 = bn0; bq1 = bn1; bq2 = bn2;
      }
      int colc = wv*16 + l15;               // 0..63 within chunk
      {
        float bias = b_in[h*DH + colc];
#pragma unroll
        for (int r = 0; r < 4; r++){
          qk[(quad*4 + r)*QKP + colc]      = (_Float16)(acc00[r] + bias);
          qk[(16 + quad*4 + r)*QKP + colc] = (_Float16)(acc01[r] + bias);
        }
      }
      {
        float bias = b_in[C_DIM + h*DH + colc];
#pragma unroll
        for (int r = 0; r < 4; r++){
          qk[(quad*4 + r)*QKP + 64 + colc]      = (_Float16)(acc10[r] + bias);
          qk[(16 + quad*4 + r)*QKP + 64 + colc] = (_Float16)(acc11[r] + bias);
        }
      }
      {
        float bias = b_in[2*C_DIM + h*DH + colc];
#pragma unroll
        for (int r = 0; r < 4; r++){
          vv[(quad*4 + r)*VVP + colc]      = (_Float16)(acc20[r] + bias);
          vv[(16 + quad*4 + r)*VVP + colc] = (_Float16)(acc21[r] + bias);
        }
      }
    }
    __syncthreads();                        // q,k,v complete for this head
    // ---- attention for head h: wave wv handles l_loc = wv, lane = nn*8+mm ----
    {
      int nn = lane >> 3, mm = lane & 7;
      int tq = wv*8 + nn;
      const _Float16* qrow = qk + tq*QKP;              // broadcast over mm
      const _Float16* krow = qk + (wv*8 + mm)*QKP + 64;
      float s = 0.f;
#pragma unroll
      for (int d8 = 0; d8 < 8; d8++){
        F8u q8, k8;
        q8.v = *(const f16x8*)(qrow + d8*8);
        k8.v = *(const f16x8*)(krow + d8*8);
#if __has_builtin(__builtin_amdgcn_fdot2)
#pragma unroll
        for (int j2 = 0; j2 < 4; j2++)
          s = __builtin_amdgcn_fdot2(q8.p[j2], k8.p[j2], s, false);
#else
#pragma unroll
        for (int j = 0; j < 8; j++) s += (float)q8.v[j] * (float)k8.v[j];
#endif
      }
      s *= 0.125f;                          // 1/sqrt(64)
      float mx = s;
#pragma unroll
      for (int o = 1; o < 8; o <<= 1) mx = fmaxf(mx, __shfl_xor(mx, o));
      float e = __expf(s - mx);
      float sum = e;
#pragma unroll
      for (int o = 1; o < 8; o <<= 1) sum += __shfl_xor(sum, o);
      float attnw = e / sum;
      // ctx: this thread owns d-slice [mm*8, mm*8+8) of token tq
      float c8[8] = {0,0,0,0,0,0,0,0};
#pragma unroll
      for (int mp = 0; mp < 8; mp++){
        float aw = __shfl(attnw, (nn<<3) | mp);
        f16x8 v8 = *(const f16x8*)(vv + (wv*8 + mp)*VVP + mm*8);
#pragma unroll
        for (int j = 0; j < 8; j++) c8[j] += aw * (float)v8[j];
      }
      f16x8 cp;
#pragma unroll
      for (int j = 0; j < 8; j++) cp[j] = (_Float16)c8[j];
      if (h == 0)      cpk0 = cp;
      else if (h == 1) cpk1 = cp;
      else if (h == 2) cpk2 = cp;
      else {
        // A is dead (last GEMM read barrier-separated): write all 4 heads' ctx
        _Float16* crow = ctx + tq*256;
        *(f16x8*)(crow + ((( 0 + mm) ^ tq))*8) = cpk0;
        *(f16x8*)(crow + ((( 8 + mm) ^ tq))*8) = cpk1;
        *(f16x8*)(crow + (((16 + mm) ^ tq))*8) = cpk2;
        *(f16x8*)(crow + (((24 + mm) ^ tq))*8) = cp;
      }
    }
  }
  __syncthreads();  // ctx complete; qk/vv dead -> att may be written

  // ================= attended = ctx @ W_out^T + b_out (fp16 MFMA) =============
  {
    f32x4 z = {0.f,0.f,0.f,0.f};
    f32x4 acc[4][2];
#pragma unroll
    for (int nt = 0; nt < 4; nt++){ acc[nt][0] = z; acc[nt][1] = z; }
    const _Float16* bp = wout + (long)(wv*32)*512 + lane*8;  // frag (wv*32+nt*8+kc)
    f16x8 bq[4], bn[4];
#pragma unroll
    for (int nt = 0; nt < 4; nt++) bq[nt] = *(const f16x8*)(bp + (nt*8)*512);
#pragma unroll
    for (int kc = 0; kc < 8; kc++){
      if (kc < 7){
#pragma unroll
        for (int nt = 0; nt < 4; nt++)
          bn[nt] = *(const f16x8*)(bp + (nt*8 + kc + 1)*512);
      }
      int s0 = quad + 4*kc;
      int r1 = 16 + l15;
      f16x8 a0 = *(const f16x8*)(ctx + l15*256 + ((s0 ^ l15))*8);
      f16x8 a1 = *(const f16x8*)(ctx + r1*256  + ((s0 ^ r1))*8);
#pragma unroll
      for (int nt = 0; nt < 4; nt++){
        acc[nt][0] = __builtin_amdgcn_mfma_f32_16x16x32_f16(a0, bq[nt], acc[nt][0], 0,0,0);
        acc[nt][1] = __builtin_amdgcn_mfma_f32_16x16x32_f16(a1, bq[nt], acc[nt][1], 0,0,0);
      }
#pragma unroll
      for (int nt = 0; nt < 4; nt++) bq[nt] = bn[nt];
    }
    __syncthreads();  // all ctx reads done; att overlay of qk/vv region is safe
#pragma unroll
    for (int nt = 0; nt < 4; nt++){
      int col = wv*64 + nt*16 + l15;
      float bias = b_out[col];
      int slot = col >> 3, j = col & 7;
#pragma unroll
      for (int r = 0; r < 4; r++){
        int row0 = quad*4 + r, row1 = 16 + quad*4 + r;
        att[row0*256 + ((slot ^ row0))*8 + j] = (_Float16)(acc[nt][0][r] + bias);
        att[row1*256 + ((slot ^ row1))*8 + j] = (_Float16)(acc[nt][1][r] + bias);
      }
    }
  }
  __syncthreads();  // att ready; ctx dead -> g1s may be written

  // ================= gate hidden: g1 = relu(att @ Wg1^T + b) =================
  {
    f32x4 acc0 = {0.f,0.f,0.f,0.f}, acc1 = {0.f,0.f,0.f,0.f};
    const _Float16* bp = wg1 + (long)(wv*8)*512 + lane*8;
    f16x8 bq = *(const f16x8*)(bp);
#pragma unroll
    for (int kc = 0; kc < 8; kc++){
      f16x8 bn;
      if (kc < 7) bn = *(const f16x8*)(bp + (kc+1)*512);
      int s0 = quad + 4*kc;
      int r1 = 16 + l15;
      f16x8 a0 = *(const f16x8*)(att + l15*256 + ((s0 ^ l15))*8);
      f16x8 a1 = *(const f16x8*)(att + r1*256  + ((s0 ^ r1))*8);
      acc0 = __builtin_amdgcn_mfma_f32_16x16x32_f16(a0, bq, acc0, 0,0,0);
      acc1 = __builtin_amdgcn_mfma_f32_16x16x32_f16(a1, bq, acc1, 0,0,0);
      bq = bn;
    }
    int col = wv*16 + l15;                  // 0..63
    float bias = b_g1[col];
#pragma unroll
    for (int r = 0; r < 4; r++){
      g1s[(quad*4 + r)*GPAD + col]      = fmaxf(acc0[r] + bias, 0.f);
      g1s[(16 + quad*4 + r)*GPAD + col] = fmaxf(acc1[r] + bias, 0.f);
    }
  }
  __syncthreads();

  // ---- gate scalar + sigmoid (8 threads per token, 32 tokens) ----
  {
    int t = tid >> 3, part = tid & 7;
    const float* g1r = g1s + t*GPAD + part*8;
    const float* w2p = w2 + part*8;
    float s = 0.f;
#pragma unroll
    for (int j = 0; j < 8; j++) s += g1r[j] * w2p[j];
    s += __shfl_xor(s, 1);
    s += __shfl_xor(s, 2);
    s += __shfl_xor(s, 4);
    if (part == 0) gl[t] = 1.f / (1.f + __expf(-(s + b2[0])));
  }
  __syncthreads();
  // ---- softmax over views (4 l's) ----
  if (tid < 4){
    float v[8]; float mx = -1e30f;
    for (int n = 0; n < 8; n++){ v[n] = gl[tid*8+n]; mx = fmaxf(mx, v[n]); }
    float sum = 0.f;
    for (int n = 0; n < 8; n++){ v[n] = __expf(v[n]-mx); sum += v[n]; }
    float inv = 1.f/sum;
    for (int n = 0; n < 8; n++) wgt[tid*8+n] = v[n]*inv;
  }
  __syncthreads();

  // ---- fused = sum_n w_n * attended, then LayerNorm over C ----
  float f8[8];
  const int lfl = tid >> 5, ccf = tid & 31;   // lfl 0..3 valid (tid<128)
  if (tid < 128){
    float wloc[8];
#pragma unroll
    for (int n = 0; n < 8; n++) wloc[n] = wgt[lfl*8+n];
#pragma unroll
    for (int j = 0; j < 8; j++) f8[j] = 0.f;
#pragma unroll
    for (int n = 0; n < 8; n++){
      int row = lfl*8 + n;
      f16x8 a8 = *(const f16x8*)(att + row*256 + ((ccf ^ row))*8);
      float aw = wloc[n];
#pragma unroll
      for (int j = 0; j < 8; j++) f8[j] += aw * (float)a8[j];
    }
    float s = 0.f, s2 = 0.f;
#pragma unroll
    for (int j = 0; j < 8; j++){ s += f8[j]; s2 += f8[j]*f8[j]; }
    red1[lfl*32 + ccf] = s;
    red2[lfl*32 + ccf] = s2;
  }
  __syncthreads();
  if (tid < 4){
    float s = 0.f, s2 = 0.f;
    for (int i = 0; i < 32; i++){ s += red1[tid*32+i]; s2 += red2[tid*32+i]; }
    float mu = s * (1.f/256.f);
    float var = s2 * (1.f/256.f) - mu*mu;
    mus[tid] = mu;
    rvs[tid] = rsqrtf(var + 1e-5f);
  }
  __syncthreads();
  if (tid < 128){
    float mu = mus[lfl], rv = rvs[lfl];
    long lg = (long)blockIdx.x * TL + lfl;
    float* op = out + lg * C_DIM + ccf*8;
    float o8[8];
#pragma unroll
    for (int j = 0; j < 8; j++){
      int c = ccf*8 + j;
      o8[j] = (f8[j]-mu)*rv*ln_g[c] + ln_b[c];
    }
    *(float4*)(op)   = make_float4(o8[0],o8[1],o8[2],o8[3]);
    *(float4*)(op+4) = make_float4(o8[4],o8[5],o8[6],o8[7]);
  }
}

extern "C" void kernel_launch(void* const* d_in, const int* in_sizes, int n_in,
                              void* d_out, int out_size, void* d_ws, size_t ws_size,
                              hipStream_t stream){
  const float* feat  = (const float*)d_in[0];
  const float* vw    = (const float*)d_in[1];
  const float* vb    = (const float*)d_in[2];
  const float* w_in  = (const float*)d_in[3];
  const float* b_in  = (const float*)d_in[4];
  const float* w_out = (const float*)d_in[5];
  const float* b_out = (const float*)d_in[6];
  const float* w_g1  = (const float*)d_in[7];
  const float* b_g1  = (const float*)d_in[8];
  const float* w2    = (const float*)d_in[9];
  const float* b2    = (const float*)d_in[10];
  const float* lng   = (const float*)d_in[11];
  const float* lnb   = (const float*)d_in[12];

  char* ws = (char*)d_ws;
  float*    view_info = (float*)ws;               //   8192 B
  _Float16* win_pk  = (_Float16*)(ws + 8192);     // 393216 B (packed fp16)
  _Float16* wout_pk = (_Float16*)(ws + 401408);   // 131072 B
  _Float16* wg1_pk  = (_Float16*)(ws + 532480);   //  32768 B   total 565248 B

  prep_kernel<<<256, 256, 0, stream>>>(vw, vb, w_in, w_out, w_g1,
                                       view_info, win_pk, wout_pk, wg1_pk);
  fused_kernel<<<L_DIM/TL, NTHREADS, 34080, stream>>>(
      feat, view_info, win_pk, wout_pk, wg1_pk,
      b_in, b_out, b_g1, w2, b2, lng, lnb, (float*)d_out);
}